// Round 16
// baseline (724.093 us; speedup 1.0000x reference)
//
#include <hip/hip_runtime.h>

#define T_STEPS 1000
#define B_SZ 64
#define N_SZ 512
#define BN_TOT (B_SZ * N_SZ)             /* 32768  */
#define TBN   ((size_t)T_STEPS * BN_TOT) /* 32.768M */

typedef __attribute__((ext_vector_type(4))) float f32x4;
typedef __attribute__((ext_vector_type(8))) short bf16x8;
typedef unsigned short ushort_t;

// ---------------------------------------------------------------------------
// GEMM1 (fp32 vector): C[M x 512] = A[M x 512] * W^T  (W row-major [512][512])
// NUMERICS CONTRACT: k-ascending single-accumulator fp32 FMA chain —
// bit-identical to np/jax BLAS microkernels (spikes depend on it).
// STRUCTURE CONTRACT (R6/R8): single-buffer LDS, staging fenced by barriers
// both sides (reg-staged dbuf spills). (R9): no address swizzle.
// (R10, kept): BK=16 -> 16.9 KB LDS, VALUBusy 75%, 385 us.
// ---------------------------------------------------------------------------
__global__ __launch_bounds__(256, 4)
void sgemm_abt(const float* __restrict__ A, const float* __restrict__ W,
               float* __restrict__ C)
{
    constexpr int K = 512;
    constexpr int BK = 16;
    constexpr int LDT = 128 + 4;
    __shared__ float As[BK][LDT];
    __shared__ float Bs[BK][LDT];

    const int tid = threadIdx.x;
    const int tx = tid & 15;
    const int ty = tid >> 4;
    const size_t m0 = (size_t)blockIdx.y * 128;
    const int n0 = blockIdx.x * 128;

    float acc[8][8];
#pragma unroll
    for (int i = 0; i < 8; ++i)
#pragma unroll
        for (int j = 0; j < 8; ++j) acc[i][j] = 0.0f;

    for (int k0 = 0; k0 < K; k0 += BK) {
#pragma unroll
        for (int p = 0; p < 2; ++p) {
            int i = tid + p * 256;       // 0..511
            int r = i >> 2;              // tile row 0..127
            int q = i & 3;               // k-quad 0..3
            float4 va = *(const float4*)(A + (m0 + r) * K + k0 + q * 4);
            As[q * 4 + 0][r] = va.x; As[q * 4 + 1][r] = va.y;
            As[q * 4 + 2][r] = va.z; As[q * 4 + 3][r] = va.w;
            float4 vb = *(const float4*)(W + (size_t)(n0 + r) * K + k0 + q * 4);
            Bs[q * 4 + 0][r] = vb.x; Bs[q * 4 + 1][r] = vb.y;
            Bs[q * 4 + 2][r] = vb.z; Bs[q * 4 + 3][r] = vb.w;
        }
        __syncthreads();
#pragma unroll
        for (int k = 0; k < BK; ++k) {
            float a[8], b[8];
            *(float4*)&a[0] = *(const float4*)&As[k][ty * 8];
            *(float4*)&a[4] = *(const float4*)&As[k][ty * 8 + 4];
            *(float4*)&b[0] = *(const float4*)&Bs[k][tx * 4];
            *(float4*)&b[4] = *(const float4*)&Bs[k][tx * 4 + 64];
#pragma unroll
            for (int i = 0; i < 8; ++i)
#pragma unroll
                for (int j = 0; j < 8; ++j)
                    acc[i][j] = fmaf(a[i], b[j], acc[i][j]);
        }
        __syncthreads();
    }

#pragma unroll
    for (int i = 0; i < 8; ++i) {
        float* cp = C + (m0 + ty * 8 + i) * 512 + n0 + tx * 4;
        *(float4*)cp        = make_float4(acc[i][0], acc[i][1], acc[i][2], acc[i][3]);
        *(float4*)(cp + 64) = make_float4(acc[i][4], acc[i][5], acc[i][6], acc[i][7]);
    }
}

// ---------------------------------------------------------------------------
// W2 -> single bf16 plane, round-to-nearest-even (validated R15: decoded
// budget 4.5 ulps, this costs ~0.07 ulp).
// ---------------------------------------------------------------------------
__global__ __launch_bounds__(256)
void w2_split(const float* __restrict__ W2, ushort_t* __restrict__ Wc)
{
    int i = blockIdx.x * 256 + threadIdx.x;      // 0..262143
    unsigned wb = __float_as_uint(W2[i]);
    unsigned rne = wb + 0x7FFFu + ((wb >> 16) & 1u);
    Wc[i] = (ushort_t)(rne >> 16);
}

// ---------------------------------------------------------------------------
// bit-octet -> 4x u32, each u32 = two bf16 lanes {0, 0x3F80} (exact 0.0/1.0)
// ---------------------------------------------------------------------------
__device__ __forceinline__ uint4 mexp8(unsigned bb)
{
    uint4 r;
    r.x = ((bb) & 1u) * 0x3F80u        | (((bb) >> 1) & 1u) * 0x3F800000u;
    r.y = (((bb) >> 2) & 1u) * 0x3F80u | (((bb) >> 3) & 1u) * 0x3F800000u;
    r.z = (((bb) >> 4) & 1u) * 0x3F80u | (((bb) >> 5) & 1u) * 0x3F800000u;
    r.w = (((bb) >> 6) & 1u) * 0x3F80u | (((bb) >> 7) & 1u) * 0x3F800000u;
    return r;
}

// ---------------------------------------------------------------------------
// GEMM2 + u-scan FUSED (R16). Block = (n-tile 128 cols, batch b); all 1000 t.
// Wave tile = 128 t-rows x 32 cols. Per 128-t chunk: R15's validated dbuf
// {mask-expand A, global_load_lds B, 16 k-steps MFMA (k-ascending -> y
// bitwise = R15)}, then in-register u-scan: t = m*16 + fq*4 + j; serialize
// across fq via __shfl (u fma order identical to li_scan -> bit-identical).
// Eliminates y round-trip (256 MB) and the li_scan launch.
// Mask rows tt>=1000 read allocated ws garbage; tt<1000 guard discards.
// mask u32 index for (t-row tt, batch b, k): tt*1024 + b*16 + (k>>5).
// ---------------------------------------------------------------------------
__global__ __launch_bounds__(256, 2)
void gemm2_li_fused(const unsigned* __restrict__ Msk,
                    const ushort_t* __restrict__ Wc,
                    const float* __restrict__ u0v,
                    const float* __restrict__ leak_i,
                    float* __restrict__ dec)
{
    __shared__ ushort_t As[2][128 * 32];
    __shared__ ushort_t Bs[2][128 * 32];

    const int tid = threadIdx.x;
    const int n0 = blockIdx.x * 128;     // col tile
    const int b  = blockIdx.y;           // batch
    const int wid = tid >> 6;
    const int lane = tid & 63;
    const int fr = lane & 15;
    const int fq = lane >> 4;
    const int wn = wid * 32;             // wave col base (within tile)

    const int rB = tid >> 2;             // B staging row 0..63 per half
    const int cB = (tid & 3) * 8;        // B staging col chunk
    const int arow = tid >> 1;           // A mask row 0..127
    const int ahalf = tid & 1;           // 16-col half

    const int col0 = n0 + wn + fr;       // this lane's two columns
    const int col1 = col0 + 16;
    const float li0 = leak_i[col0];
    const float li1 = leak_i[col1];
    float u0 = u0v[b * 512 + col0];
    float u1 = u0v[b * 512 + col1];

    f32x4 acc[8][2] = {};
    unsigned mword;

#define MLOAD(it)                                                            \
    {                                                                        \
        const int tt_ = ((it) >> 4) * 128 + arow;                            \
        mword = Msk[(size_t)tt_ * 1024 + b * 16 + ((it) & 15)];              \
    }
#define STAGE_B(buf, it)                                                     \
    {                                                                        \
        const int k0_ = ((it) & 15) * 32;                                    \
        _Pragma("unroll")                                                    \
        for (int i = 0; i < 2; ++i) {                                        \
            __builtin_amdgcn_global_load_lds(                                \
                (const __attribute__((address_space(1))) unsigned int*)      \
                    (Wc + (size_t)(n0 + i * 64 + rB) * 512 + k0_ + cB),      \
                (__attribute__((address_space(3))) unsigned int*)            \
                    (Bs[buf] + i * 2048 + tid * 8),                          \
                16, 0, 0);                                                   \
        }                                                                    \
    }
#define MSTORE(buf)                                                          \
    {                                                                        \
        unsigned h_ = (mword >> (ahalf * 16)) & 0xFFFFu;                     \
        *(uint4*)(As[buf] + arow * 32 + ahalf * 16)     = mexp8(h_ & 0xFFu); \
        *(uint4*)(As[buf] + arow * 32 + ahalf * 16 + 8) = mexp8(h_ >> 8);    \
    }

    MLOAD(0);
    STAGE_B(0, 0);
    MSTORE(0);
    asm volatile("s_waitcnt vmcnt(0)" ::: "memory");
    __syncthreads();

    int cur = 0;
    for (int it = 0; it < 128; ++it) {
        if (it + 1 < 128) {
            MLOAD(it + 1);
            STAGE_B(cur ^ 1, it + 1);
        }

        bf16x8 a[8], bb[2];
#pragma unroll
        for (int m = 0; m < 8; ++m)
            a[m] = *(const bf16x8*)(As[cur] + (m * 16 + fr) * 32 + fq * 8);
#pragma unroll
        for (int n = 0; n < 2; ++n)
            bb[n] = *(const bf16x8*)(Bs[cur] + (wn + n * 16 + fr) * 32 + fq * 8);
#pragma unroll
        for (int m = 0; m < 8; ++m)
#pragma unroll
            for (int n = 0; n < 2; ++n)
                acc[m][n] = __builtin_amdgcn_mfma_f32_16x16x32_bf16(
                    a[m], bb[n], acc[m][n], 0, 0, 0);

        if (it + 1 < 128)
            MSTORE(cur ^ 1);

        if ((it & 15) == 15) {           // chunk complete: u-scan + reset
            const int cb = (it >> 4) * 128;
#pragma unroll
            for (int m = 0; m < 8; ++m) {
#pragma unroll
                for (int q = 0; q < 4; ++q) {
                    const int tb = cb + m * 16 + q * 4;
                    if (fq == q) {
#pragma unroll
                        for (int j = 0; j < 4; ++j) {
                            if (tb + j < T_STEPS) {
                                u0 = fmaf(li0, u0, acc[m][0][j]);
                                u1 = fmaf(li1, u1, acc[m][1][j]);
                                size_t o = (size_t)(tb + j) * BN_TOT + b * 512;
                                dec[o + col0] = u0;
                                dec[o + col1] = u1;
                            }
                        }
                    }
                    u0 = __shfl(u0, q * 16 + fr);
                    u1 = __shfl(u1, q * 16 + fr);
                }
            }
#pragma unroll
            for (int m = 0; m < 8; ++m) {
                acc[m][0] = (f32x4){0.f, 0.f, 0.f, 0.f};
                acc[m][1] = (f32x4){0.f, 0.f, 0.f, 0.f};
            }
        }

        asm volatile("s_waitcnt vmcnt(0)" ::: "memory");
        __syncthreads();
        cur ^= 1;
    }
#undef MLOAD
#undef STAGE_B
#undef MSTORE
}

// ---------------------------------------------------------------------------
// scan1: per-(b,n) LIF recurrence, 8-deep prefetch. Arithmetic per step
// unchanged (bit-exact). Emits spike BITMASK via __ballot:
// Msk[t*512 + (idx>>6)] bit l = spike of idx=(idx&~63)|l.
// ---------------------------------------------------------------------------
__global__ __launch_bounds__(128)
void lif_scan(const float* __restrict__ ff, const float* __restrict__ st0,
              const float* __restrict__ leak_v, const float* __restrict__ thresh,
              float* __restrict__ spikes, float* __restrict__ states,
              unsigned long long* __restrict__ Msk)
{
    const int idx = blockIdx.x * 128 + threadIdx.x;
    const int n = idx & (N_SZ - 1);
    const int b = idx >> 9;

    float v = st0[idx];
    float s = st0[BN_TOT + idx];
    const float lv = leak_v[n];
    const float th = thresh[n];

    const float* fp = ff + (size_t)b * T_STEPS * N_SZ + n;
    float* sp  = spikes + idx;
    float* stp = states + idx;
    const int wslot = idx >> 6;
    const bool wlead = ((threadIdx.x & 63) == 0);

    float f[8];
#pragma unroll
    for (int j = 0; j < 8; ++j) f[j] = fp[(size_t)j * N_SZ];

    for (int t = 0; t < T_STEPS; t += 8) {
        float g[8];
#pragma unroll
        for (int j = 0; j < 8; ++j) g[j] = 0.f;
        if (t + 8 < T_STEPS) {
            const float* q = fp + (size_t)(t + 8) * N_SZ;
#pragma unroll
            for (int j = 0; j < 8; ++j) g[j] = q[(size_t)j * N_SZ];
        }
#pragma unroll
        for (int j = 0; j < 8; ++j) {
            v = lv * v * (1.0f - s) + f[j];
            s = (v > th) ? 1.0f : 0.0f;
            size_t o  = (size_t)(t + j) * BN_TOT;
            size_t o2 = (size_t)(t + j) * (2 * BN_TOT);
            sp[o] = s;
            stp[o2] = v;
            stp[o2 + BN_TOT] = s;
            unsigned long long bm = __ballot(s != 0.0f);
            if (Msk && wlead)
                Msk[(size_t)(t + j) * 512 + wslot] = bm;
        }
#pragma unroll
        for (int j = 0; j < 8; ++j) f[j] = g[j];
    }
}

// ---------------------------------------------------------------------------
// scan2 (FALLBACK PATH ONLY): u[t] = leak_i*u[t-1] + y[t], in place.
// ---------------------------------------------------------------------------
__global__ __launch_bounds__(128)
void li_scan(float* __restrict__ dec, const float* __restrict__ u0,
             const float* __restrict__ leak_i)
{
    const int idx = blockIdx.x * 128 + threadIdx.x;
    const int n = idx & (N_SZ - 1);

    float u = u0[idx];
    const float li = leak_i[n];
    float* p = dec + idx;

    float y[8];
#pragma unroll
    for (int j = 0; j < 8; ++j) y[j] = p[(size_t)j * BN_TOT];

    for (int t = 0; t < T_STEPS; t += 8) {
        float g[8];
#pragma unroll
        for (int j = 0; j < 8; ++j) g[j] = 0.f;
        if (t + 8 < T_STEPS) {
            float* q = p + (size_t)(t + 8) * BN_TOT;
#pragma unroll
            for (int j = 0; j < 8; ++j) g[j] = q[(size_t)j * BN_TOT];
        }
#pragma unroll
        for (int j = 0; j < 8; ++j) {
            u = fmaf(li, u, y[j]);
            p[(size_t)(t + j) * BN_TOT] = u;
        }
#pragma unroll
        for (int j = 0; j < 8; ++j) y[j] = g[j];
    }
}

// ---------------------------------------------------------------------------
extern "C" void kernel_launch(void* const* d_in, const int* in_sizes, int n_in,
                              void* d_out, int out_size, void* d_ws, size_t ws_size,
                              hipStream_t stream)
{
    (void)in_sizes; (void)n_in; (void)out_size;

    const float* X     = (const float*)d_in[0];
    const float* st_sn = (const float*)d_in[1];
    const float* st_li = (const float*)d_in[2];
    const float* W1    = (const float*)d_in[3];
    const float* W2    = (const float*)d_in[4];
    const float* lv    = (const float*)d_in[5];
    const float* li    = (const float*)d_in[6];
    const float* th    = (const float*)d_in[7];

    float* spikes = (float*)d_out;                // [T][B][N]
    float* states = spikes + TBN;                 // [T][2][B][N]
    float* dec    = states + 2 * TBN;             // [T][B][N]

    // ws layout: Wc [512][512] bf16 (0.5 MiB) + spike mask [1000][512] u64
    // (4 MiB) + slack (fused kernel reads ~96 KB past mask end for t>=1000,
    // discarded by guard — ws_size is far larger).
    const size_t WS_NEED = (size_t)512 * 512 * 2 + (size_t)1024 * 512 * 8;
    const bool use_mfma = (ws_size >= WS_NEED);
    ushort_t* Wc = (ushort_t*)d_ws;
    unsigned long long* Msk = (unsigned long long*)(Wc + (size_t)512 * 512);

    const dim3 gemm_grid(4, 500), gemm_block(256);
    const dim3 scan_grid(BN_TOT / 128), scan_block(128);

    if (use_mfma)
        w2_split<<<dim3(1024), dim3(256), 0, stream>>>(W2, Wc);

    // 1) FF = X @ W1^T (exact fp32 sequential-FMA path) -> dec [b][t][n]
    sgemm_abt<<<gemm_grid, gemm_block, 0, stream>>>(X, W1, dec);

    // 2) (v,s) scan; spikes + states (+ spike bitmask into ws)
    lif_scan<<<scan_grid, scan_block, 0, stream>>>(dec, st_sn, lv, th,
                                                   spikes, states,
                                                   use_mfma ? Msk
                                                            : (unsigned long long*)0);

    // 3+4) y = s @ W2^T and u-scan, fused -> dec [t][b][n]
    if (use_mfma) {
        gemm2_li_fused<<<dim3(4, 64), dim3(256), 0, stream>>>(
            (const unsigned*)Msk, Wc, st_li, li, dec);
    } else {
        sgemm_abt<<<gemm_grid, gemm_block, 0, stream>>>(spikes, W2, dec);
        li_scan<<<scan_grid, scan_block, 0, stream>>>(dec, st_li, li);
    }
}

// Round 17
// 717.275 us; speedup vs baseline: 1.0095x; 1.0095x over previous
//
#include <hip/hip_runtime.h>

#define T_STEPS 1000
#define B_SZ 64
#define N_SZ 512
#define BN_TOT (B_SZ * N_SZ)             /* 32768  */
#define TBN   ((size_t)T_STEPS * BN_TOT) /* 32.768M */

typedef __attribute__((ext_vector_type(4))) float f32x4;
typedef __attribute__((ext_vector_type(8))) short bf16x8;
typedef __attribute__((ext_vector_type(4))) unsigned uint32x4;
typedef unsigned short ushort_t;

// ---------------------------------------------------------------------------
// GEMM1 (fp32 vector): C[M x 512] = A[M x 512] * W^T  (W row-major [512][512])
// NUMERICS CONTRACT: k-ascending single-accumulator fp32 FMA chain —
// bit-identical to np/jax BLAS microkernels (spikes depend on it).
// STRUCTURE CONTRACT (R6/R8): single-buffer LDS, staging fenced by barriers
// both sides (reg-staged dbuf spills). (R9): no address swizzle.
// (R10, kept): BK=16 -> 16.9 KB LDS, VALUBusy 75%, 385 us.
// ---------------------------------------------------------------------------
__global__ __launch_bounds__(256, 4)
void sgemm_abt(const float* __restrict__ A, const float* __restrict__ W,
               float* __restrict__ C)
{
    constexpr int K = 512;
    constexpr int BK = 16;
    constexpr int LDT = 128 + 4;
    __shared__ float As[BK][LDT];
    __shared__ float Bs[BK][LDT];

    const int tid = threadIdx.x;
    const int tx = tid & 15;
    const int ty = tid >> 4;
    const size_t m0 = (size_t)blockIdx.y * 128;
    const int n0 = blockIdx.x * 128;

    float acc[8][8];
#pragma unroll
    for (int i = 0; i < 8; ++i)
#pragma unroll
        for (int j = 0; j < 8; ++j) acc[i][j] = 0.0f;

    for (int k0 = 0; k0 < K; k0 += BK) {
#pragma unroll
        for (int p = 0; p < 2; ++p) {
            int i = tid + p * 256;       // 0..511
            int r = i >> 2;              // tile row 0..127
            int q = i & 3;               // k-quad 0..3
            float4 va = *(const float4*)(A + (m0 + r) * K + k0 + q * 4);
            As[q * 4 + 0][r] = va.x; As[q * 4 + 1][r] = va.y;
            As[q * 4 + 2][r] = va.z; As[q * 4 + 3][r] = va.w;
            float4 vb = *(const float4*)(W + (size_t)(n0 + r) * K + k0 + q * 4);
            Bs[q * 4 + 0][r] = vb.x; Bs[q * 4 + 1][r] = vb.y;
            Bs[q * 4 + 2][r] = vb.z; Bs[q * 4 + 3][r] = vb.w;
        }
        __syncthreads();
#pragma unroll
        for (int k = 0; k < BK; ++k) {
            float a[8], b[8];
            *(float4*)&a[0] = *(const float4*)&As[k][ty * 8];
            *(float4*)&a[4] = *(const float4*)&As[k][ty * 8 + 4];
            *(float4*)&b[0] = *(const float4*)&Bs[k][tx * 4];
            *(float4*)&b[4] = *(const float4*)&Bs[k][tx * 4 + 64];
#pragma unroll
            for (int i = 0; i < 8; ++i)
#pragma unroll
                for (int j = 0; j < 8; ++j)
                    acc[i][j] = fmaf(a[i], b[j], acc[i][j]);
        }
        __syncthreads();
    }

#pragma unroll
    for (int i = 0; i < 8; ++i) {
        float* cp = C + (m0 + ty * 8 + i) * 512 + n0 + tx * 4;
        *(float4*)cp        = make_float4(acc[i][0], acc[i][1], acc[i][2], acc[i][3]);
        *(float4*)(cp + 64) = make_float4(acc[i][4], acc[i][5], acc[i][6], acc[i][7]);
    }
}

// ---------------------------------------------------------------------------
// W2 -> single bf16 plane, round-to-nearest-even (validated R15: decoded
// budget 4.5 ulps, this costs ~0.07 ulp; absmax stayed 0.125).
// ---------------------------------------------------------------------------
__global__ __launch_bounds__(256)
void w2_split(const float* __restrict__ W2, ushort_t* __restrict__ Wc)
{
    int i = blockIdx.x * 256 + threadIdx.x;      // 0..262143
    unsigned wb = __float_as_uint(W2[i]);
    unsigned rne = wb + 0x7FFFu + ((wb >> 16) & 1u);
    Wc[i] = (ushort_t)(rne >> 16);
}

// ---------------------------------------------------------------------------
// bit-octet -> bf16x8 with values {0.0, 1.0} (exact); bit j -> element j.
// ---------------------------------------------------------------------------
union bfcast { uint32x4 u; bf16x8 v; };
__device__ __forceinline__ bf16x8 mexp8v(unsigned bb)
{
    bfcast c;
    c.u.x = (bb & 1u)        * 0x3F80u | ((bb >> 1) & 1u) * 0x3F800000u;
    c.u.y = ((bb >> 2) & 1u) * 0x3F80u | ((bb >> 3) & 1u) * 0x3F800000u;
    c.u.z = ((bb >> 4) & 1u) * 0x3F80u | ((bb >> 5) & 1u) * 0x3F800000u;
    c.u.w = ((bb >> 6) & 1u) * 0x3F80u | ((bb >> 7) & 1u) * 0x3F800000u;
    return c.v;
}

// ---------------------------------------------------------------------------
// GEMM2 (bf16 MFMA): C[64000 x 512] fp32 = spikes @ Wc^T, K'=512.
// R17: A-side LDS removed — each lane reads its own 4 mask dwords per tile
// (L2-hot, 64B-row-stride 16-lane gather; tiny vs R14's failed 64B B-gather)
// and expands bits->bf16 {0,1.0} in-register. B pipeline unchanged from the
// validated R15 skeleton (global_load_lds + LDS dbuf + per-tile drain).
// Removes 2 ds_write + 4 ds_read_b128 per iter, frees 16 KB LDS;
// launch_bounds(256,3) raises residency 2 -> ~4 blocks/CU.
// A values + MFMA order identical to R15 -> decoded bit-identical.
// mask u32 word for A row m (=t*64+b), k: m*16 + (k>>5); byte fq = k-cols
// fq*8..fq*8+7 of k-tile t.
// ---------------------------------------------------------------------------
__global__ __launch_bounds__(256, 3)
void gemm2_mfma(const unsigned* __restrict__ Msk, const ushort_t* __restrict__ Wc,
                float* __restrict__ C)
{
    constexpr int NT = 512 / 32;         // 16
    __shared__ ushort_t Bs[2][128 * 32];

    const int tid = threadIdx.x;
    const int m0 = blockIdx.y * 128;
    const int n0 = blockIdx.x * 128;
    const int wid = tid >> 6;
    const int lane = tid & 63;
    const int wm = (wid >> 1) * 64;
    const int wn = (wid & 1) * 64;
    const int fr = lane & 15;
    const int fq = lane >> 4;
    const int ash = fq * 8;              // byte of the mask word

    f32x4 acc[4][4] = {};

    const int rB = tid >> 2;             // B staging row 0..63 per half
    const int cB = (tid & 3) * 8;        // B staging col chunk
    // per-lane A mask row bases: row = m0 + wm + m*16 + fr, 16 words/row
    const size_t arow0 = (size_t)(m0 + wm + fr) * 16;

    unsigned mwc[4], mwn[4];

#define STAGE_B(buf, t)                                                      \
    {                                                                        \
        const int k0_ = (t) * 32;                                            \
        _Pragma("unroll")                                                    \
        for (int i = 0; i < 2; ++i) {                                        \
            __builtin_amdgcn_global_load_lds(                                \
                (const __attribute__((address_space(1))) unsigned int*)      \
                    (Wc + (size_t)(n0 + i * 64 + rB) * 512 + k0_ + cB),      \
                (__attribute__((address_space(3))) unsigned int*)            \
                    (Bs[buf] + i * 2048 + tid * 8),                          \
                16, 0, 0);                                                   \
        }                                                                    \
    }
#define MLOADA(dst, t)                                                       \
    {                                                                        \
        _Pragma("unroll")                                                    \
        for (int m_ = 0; m_ < 4; ++m_)                                       \
            dst[m_] = Msk[arow0 + (size_t)m_ * 256 + (t)];                   \
    }

    MLOADA(mwc, 0);
    STAGE_B(0, 0);
    asm volatile("s_waitcnt vmcnt(0)" ::: "memory");
    __syncthreads();

    int cur = 0;
    for (int t = 0; t < NT; ++t) {
        if (t + 1 < NT) {
            STAGE_B(cur ^ 1, t + 1);     // B loads in flight during MFMA
            MLOADA(mwn, t + 1);          // A mask words for next tile
        }

        bf16x8 a[4], b[4];
#pragma unroll
        for (int m = 0; m < 4; ++m)
            a[m] = mexp8v((mwc[m] >> ash) & 0xFFu);
#pragma unroll
        for (int n = 0; n < 4; ++n)
            b[n] = *(const bf16x8*)(Bs[cur] + (wn + n * 16 + fr) * 32 + fq * 8);
#pragma unroll
        for (int m = 0; m < 4; ++m)
#pragma unroll
            for (int n = 0; n < 4; ++n)
                acc[m][n] = __builtin_amdgcn_mfma_f32_16x16x32_bf16(
                    a[m], b[n], acc[m][n], 0, 0, 0);

        asm volatile("s_waitcnt vmcnt(0)" ::: "memory");
        __syncthreads();
        cur ^= 1;
#pragma unroll
        for (int m = 0; m < 4; ++m) mwc[m] = mwn[m];
    }
#undef STAGE_B
#undef MLOADA

#pragma unroll
    for (int m = 0; m < 4; ++m) {
        const int row = m0 + wm + m * 16 + fq * 4;
#pragma unroll
        for (int n = 0; n < 4; ++n) {
            const int col = n0 + wn + n * 16 + fr;
#pragma unroll
            for (int j = 0; j < 4; ++j)
                C[(size_t)(row + j) * 512 + col] = acc[m][n][j];
        }
    }
}

// ---------------------------------------------------------------------------
// scan1: per-(b,n) LIF recurrence, 8-deep prefetch. Arithmetic per step
// unchanged (bit-exact). Emits spike BITMASK via __ballot:
// Msk[t*512 + (idx>>6)] bit l = spike of idx=(idx&~63)|l.
// ---------------------------------------------------------------------------
__global__ __launch_bounds__(128)
void lif_scan(const float* __restrict__ ff, const float* __restrict__ st0,
              const float* __restrict__ leak_v, const float* __restrict__ thresh,
              float* __restrict__ spikes, float* __restrict__ states,
              unsigned long long* __restrict__ Msk)
{
    const int idx = blockIdx.x * 128 + threadIdx.x;
    const int n = idx & (N_SZ - 1);
    const int b = idx >> 9;

    float v = st0[idx];
    float s = st0[BN_TOT + idx];
    const float lv = leak_v[n];
    const float th = thresh[n];

    const float* fp = ff + (size_t)b * T_STEPS * N_SZ + n;
    float* sp  = spikes + idx;
    float* stp = states + idx;
    const int wslot = idx >> 6;
    const bool wlead = ((threadIdx.x & 63) == 0);

    float f[8];
#pragma unroll
    for (int j = 0; j < 8; ++j) f[j] = fp[(size_t)j * N_SZ];

    for (int t = 0; t < T_STEPS; t += 8) {
        float g[8];
#pragma unroll
        for (int j = 0; j < 8; ++j) g[j] = 0.f;
        if (t + 8 < T_STEPS) {
            const float* q = fp + (size_t)(t + 8) * N_SZ;
#pragma unroll
            for (int j = 0; j < 8; ++j) g[j] = q[(size_t)j * N_SZ];
        }
#pragma unroll
        for (int j = 0; j < 8; ++j) {
            v = lv * v * (1.0f - s) + f[j];
            s = (v > th) ? 1.0f : 0.0f;
            size_t o  = (size_t)(t + j) * BN_TOT;
            size_t o2 = (size_t)(t + j) * (2 * BN_TOT);
            sp[o] = s;
            stp[o2] = v;
            stp[o2 + BN_TOT] = s;
            unsigned long long bm = __ballot(s != 0.0f);
            if (Msk && wlead)
                Msk[(size_t)(t + j) * 512 + wslot] = bm;
        }
#pragma unroll
        for (int j = 0; j < 8; ++j) f[j] = g[j];
    }
}

// ---------------------------------------------------------------------------
// scan2: u[t] = leak_i*u[t-1] + y[t], in place over dec ([t][b][n]);
// 8-deep prefetch.
// ---------------------------------------------------------------------------
__global__ __launch_bounds__(128)
void li_scan(float* __restrict__ dec, const float* __restrict__ u0,
              const float* __restrict__ leak_i)
{
    const int idx = blockIdx.x * 128 + threadIdx.x;
    const int n = idx & (N_SZ - 1);

    float u = u0[idx];
    const float li = leak_i[n];
    float* p = dec + idx;

    float y[8];
#pragma unroll
    for (int j = 0; j < 8; ++j) y[j] = p[(size_t)j * BN_TOT];

    for (int t = 0; t < T_STEPS; t += 8) {
        float g[8];
#pragma unroll
        for (int j = 0; j < 8; ++j) g[j] = 0.f;
        if (t + 8 < T_STEPS) {
            float* q = p + (size_t)(t + 8) * BN_TOT;
#pragma unroll
            for (int j = 0; j < 8; ++j) g[j] = q[(size_t)j * BN_TOT];
        }
#pragma unroll
        for (int j = 0; j < 8; ++j) {
            u = fmaf(li, u, y[j]);
            p[(size_t)(t + j) * BN_TOT] = u;
        }
#pragma unroll
        for (int j = 0; j < 8; ++j) y[j] = g[j];
    }
}

// ---------------------------------------------------------------------------
extern "C" void kernel_launch(void* const* d_in, const int* in_sizes, int n_in,
                              void* d_out, int out_size, void* d_ws, size_t ws_size,
                              hipStream_t stream)
{
    (void)in_sizes; (void)n_in; (void)out_size;

    const float* X     = (const float*)d_in[0];
    const float* st_sn = (const float*)d_in[1];
    const float* st_li = (const float*)d_in[2];
    const float* W1    = (const float*)d_in[3];
    const float* W2    = (const float*)d_in[4];
    const float* lv    = (const float*)d_in[5];
    const float* li    = (const float*)d_in[6];
    const float* th    = (const float*)d_in[7];

    float* spikes = (float*)d_out;                // [T][B][N]
    float* states = spikes + TBN;                 // [T][2][B][N]
    float* dec    = states + 2 * TBN;             // [T][B][N]

    // ws layout: Wc [512][512] bf16 (0.5 MiB) + spike mask [1000][512] u64 (4 MiB)
    const size_t WS_NEED = (size_t)512 * 512 * 2 + (size_t)1000 * 512 * 8;
    const bool use_mfma = (ws_size >= WS_NEED);
    ushort_t* Wc = (ushort_t*)d_ws;
    unsigned long long* Msk = (unsigned long long*)(Wc + (size_t)512 * 512);

    const dim3 gemm_grid(4, 500), gemm_block(256);
    const dim3 scan_grid(BN_TOT / 128), scan_block(128);

    if (use_mfma)
        w2_split<<<dim3(1024), dim3(256), 0, stream>>>(W2, Wc);

    // 1) FF = X @ W1^T (exact fp32 sequential-FMA path) -> dec [b][t][n]
    sgemm_abt<<<gemm_grid, gemm_block, 0, stream>>>(X, W1, dec);

    // 2) (v,s) scan; spikes + states (+ spike bitmask into ws)
    lif_scan<<<scan_grid, scan_block, 0, stream>>>(dec, st_sn, lv, th,
                                                   spikes, states,
                                                   use_mfma ? Msk
                                                            : (unsigned long long*)0);

    // 3) Y = spikes @ W2^T -> dec [t][b][n]
    if (use_mfma)
        gemm2_mfma<<<gemm_grid, gemm_block, 0, stream>>>((const unsigned*)Msk,
                                                         Wc, dec);
    else
        sgemm_abt<<<gemm_grid, gemm_block, 0, stream>>>(spikes, W2, dec);

    // 4) u scan in place over dec
    li_scan<<<scan_grid, scan_block, 0, stream>>>(dec, st_li, li);
}

// Round 18
// 691.438 us; speedup vs baseline: 1.0472x; 1.0374x over previous
//
#include <hip/hip_runtime.h>

#define T_STEPS 1000
#define B_SZ 64
#define N_SZ 512
#define BN_TOT (B_SZ * N_SZ)             /* 32768  */
#define TBN   ((size_t)T_STEPS * BN_TOT) /* 32.768M */

typedef __attribute__((ext_vector_type(4))) float f32x4;
typedef __attribute__((ext_vector_type(8))) short bf16x8;
typedef unsigned short ushort_t;

// ---------------------------------------------------------------------------
// GEMM1 (fp32 vector): C[M x 512] = A[M x 512] * W^T  (W row-major [512][512])
// NUMERICS CONTRACT: k-ascending single-accumulator fp32 FMA chain —
// bit-identical to np/jax BLAS microkernels (spikes depend on it).
// STRUCTURE CONTRACT (R6/R8): single-buffer LDS, staging fenced by barriers
// both sides (reg-staged dbuf spills). (R9): no address swizzle.
// (R10, kept): BK=16 -> 16.9 KB LDS, VALUBusy 75%, 385 us.
// ---------------------------------------------------------------------------
__global__ __launch_bounds__(256, 4)
void sgemm_abt(const float* __restrict__ A, const float* __restrict__ W,
               float* __restrict__ C)
{
    constexpr int K = 512;
    constexpr int BK = 16;
    constexpr int LDT = 128 + 4;
    __shared__ float As[BK][LDT];
    __shared__ float Bs[BK][LDT];

    const int tid = threadIdx.x;
    const int tx = tid & 15;
    const int ty = tid >> 4;
    const size_t m0 = (size_t)blockIdx.y * 128;
    const int n0 = blockIdx.x * 128;

    float acc[8][8];
#pragma unroll
    for (int i = 0; i < 8; ++i)
#pragma unroll
        for (int j = 0; j < 8; ++j) acc[i][j] = 0.0f;

    for (int k0 = 0; k0 < K; k0 += BK) {
#pragma unroll
        for (int p = 0; p < 2; ++p) {
            int i = tid + p * 256;       // 0..511
            int r = i >> 2;              // tile row 0..127
            int q = i & 3;               // k-quad 0..3
            float4 va = *(const float4*)(A + (m0 + r) * K + k0 + q * 4);
            As[q * 4 + 0][r] = va.x; As[q * 4 + 1][r] = va.y;
            As[q * 4 + 2][r] = va.z; As[q * 4 + 3][r] = va.w;
            float4 vb = *(const float4*)(W + (size_t)(n0 + r) * K + k0 + q * 4);
            Bs[q * 4 + 0][r] = vb.x; Bs[q * 4 + 1][r] = vb.y;
            Bs[q * 4 + 2][r] = vb.z; Bs[q * 4 + 3][r] = vb.w;
        }
        __syncthreads();
#pragma unroll
        for (int k = 0; k < BK; ++k) {
            float a[8], b[8];
            *(float4*)&a[0] = *(const float4*)&As[k][ty * 8];
            *(float4*)&a[4] = *(const float4*)&As[k][ty * 8 + 4];
            *(float4*)&b[0] = *(const float4*)&Bs[k][tx * 4];
            *(float4*)&b[4] = *(const float4*)&Bs[k][tx * 4 + 64];
#pragma unroll
            for (int i = 0; i < 8; ++i)
#pragma unroll
                for (int j = 0; j < 8; ++j)
                    acc[i][j] = fmaf(a[i], b[j], acc[i][j]);
        }
        __syncthreads();
    }

#pragma unroll
    for (int i = 0; i < 8; ++i) {
        float* cp = C + (m0 + ty * 8 + i) * 512 + n0 + tx * 4;
        *(float4*)cp        = make_float4(acc[i][0], acc[i][1], acc[i][2], acc[i][3]);
        *(float4*)(cp + 64) = make_float4(acc[i][4], acc[i][5], acc[i][6], acc[i][7]);
    }
}

// ---------------------------------------------------------------------------
// W2 -> single bf16 plane, round-to-nearest-even (validated R15: decoded
// budget 4.5 ulps, this costs ~0.07 ulp; absmax stayed 0.125).
// ---------------------------------------------------------------------------
__global__ __launch_bounds__(256)
void w2_split(const float* __restrict__ W2, ushort_t* __restrict__ Wc)
{
    int i = blockIdx.x * 256 + threadIdx.x;      // 0..262143
    unsigned wb = __float_as_uint(W2[i]);
    unsigned rne = wb + 0x7FFFu + ((wb >> 16) & 1u);
    Wc[i] = (ushort_t)(rne >> 16);
}

// ---------------------------------------------------------------------------
// bit-octet -> 4x u32, each u32 = two bf16 lanes {0, 0x3F80} (exact 0.0/1.0)
// ---------------------------------------------------------------------------
__device__ __forceinline__ uint4 mexp8(unsigned bb)
{
    uint4 r;
    r.x = ((bb) & 1u) * 0x3F80u        | (((bb) >> 1) & 1u) * 0x3F800000u;
    r.y = (((bb) >> 2) & 1u) * 0x3F80u | (((bb) >> 3) & 1u) * 0x3F800000u;
    r.z = (((bb) >> 4) & 1u) * 0x3F80u | (((bb) >> 5) & 1u) * 0x3F800000u;
    r.w = (((bb) >> 6) & 1u) * 0x3F80u | (((bb) >> 7) & 1u) * 0x3F800000u;
    return r;
}

// ---------------------------------------------------------------------------
// GEMM2 (bf16 MFMA): C[64000 x 512] fp32 = spikes @ Wc^T, K'=512 (1-term W2).
// R15-validated skeleton — the local optimum for this decomposition:
// R14 (zero-LDS), R16 (u-scan fusion), R17 (A-reg expand) all regressed.
// A from spike bitmask (L2-hot): 1 mask u32 per thread per tile, expand
// bits -> bf16 {0,1.0} (exact) into As; B via global_load_lds, dbuf.
// mask32 word for A row m, col k: m*16 + (k>>5), bit (k&31).
// ---------------------------------------------------------------------------
__global__ __launch_bounds__(256, 2)
void gemm2_mfma(const unsigned* __restrict__ Msk, const ushort_t* __restrict__ Wc,
                float* __restrict__ C)
{
    constexpr int NT = 512 / 32;         // 16
    __shared__ ushort_t As[2][128 * 32];
    __shared__ ushort_t Bs[2][128 * 32];

    const int tid = threadIdx.x;
    const int m0 = blockIdx.y * 128;
    const int n0 = blockIdx.x * 128;
    const int wid = tid >> 6;
    const int lane = tid & 63;
    const int wm = (wid >> 1) * 64;
    const int wn = (wid & 1) * 64;
    const int fr = lane & 15;
    const int fq = lane >> 4;

    f32x4 acc[4][4] = {};

    const int rA = tid >> 2;             // 0..63 rows per half-tile (B stage)
    const int cA = (tid & 3) * 8;        // bf16 col within 32 (B stage)
    const size_t mrow0 = (size_t)(m0 + (tid >> 2)) * 16;
    const size_t mrow1 = (size_t)(m0 + 64 + (tid >> 2)) * 16;
    const int qsh = (tid & 3) * 8;       // bit group within the u32

    unsigned mw0, mw1;

#define STAGE_B(buf, t)                                                      \
    {                                                                        \
        const int k0_ = (t) * 32;                                            \
        _Pragma("unroll")                                                    \
        for (int i = 0; i < 2; ++i) {                                        \
            __builtin_amdgcn_global_load_lds(                                \
                (const __attribute__((address_space(1))) unsigned int*)      \
                    (Wc + (size_t)(n0 + i * 64 + rA) * 512 + k0_ + cA),      \
                (__attribute__((address_space(3))) unsigned int*)            \
                    (Bs[buf] + i * 2048 + tid * 8),                          \
                16, 0, 0);                                                   \
        }                                                                    \
    }
#define MLOAD(t)                                                             \
    {                                                                        \
        const int mword = (t);           /* k0>>5 = t (K'=512, one pass) */  \
        mw0 = Msk[mrow0 + mword];                                            \
        mw1 = Msk[mrow1 + mword];                                            \
    }
#define MSTORE(buf)                                                          \
    {                                                                        \
        *(uint4*)(As[buf] + tid * 8)        = mexp8((mw0 >> qsh) & 0xFFu);   \
        *(uint4*)(As[buf] + 2048 + tid * 8) = mexp8((mw1 >> qsh) & 0xFFu);   \
    }

    MLOAD(0);
    STAGE_B(0, 0);
    MSTORE(0);
    asm volatile("s_waitcnt vmcnt(0)" ::: "memory");
    __syncthreads();

    int cur = 0;
    for (int t = 0; t < NT; ++t) {
        if (t + 1 < NT) {
            MLOAD(t + 1);                // in flight during MFMA
            STAGE_B(cur ^ 1, t + 1);
        }

        bf16x8 a[4], b[4];
#pragma unroll
        for (int m = 0; m < 4; ++m)
            a[m] = *(const bf16x8*)(As[cur] + (wm + m * 16 + fr) * 32 + fq * 8);
#pragma unroll
        for (int n = 0; n < 4; ++n)
            b[n] = *(const bf16x8*)(Bs[cur] + (wn + n * 16 + fr) * 32 + fq * 8);
#pragma unroll
        for (int m = 0; m < 4; ++m)
#pragma unroll
            for (int n = 0; n < 4; ++n)
                acc[m][n] = __builtin_amdgcn_mfma_f32_16x16x32_bf16(
                    a[m], b[n], acc[m][n], 0, 0, 0);

        if (t + 1 < NT)
            MSTORE(cur ^ 1);             // expand after MFMA (latency hidden)

        asm volatile("s_waitcnt vmcnt(0)" ::: "memory");
        __syncthreads();
        cur ^= 1;
    }
#undef STAGE_B
#undef MLOAD
#undef MSTORE

#pragma unroll
    for (int m = 0; m < 4; ++m) {
        const int row = m0 + wm + m * 16 + fq * 4;
#pragma unroll
        for (int n = 0; n < 4; ++n) {
            const int col = n0 + wn + n * 16 + fr;
#pragma unroll
            for (int j = 0; j < 4; ++j)
                C[(size_t)(row + j) * 512 + col] = acc[m][n][j];
        }
    }
}

// ---------------------------------------------------------------------------
// scan1: per-(b,n) LIF recurrence, 8-deep prefetch. Arithmetic per step
// unchanged (bit-exact). Emits spike BITMASK via __ballot:
// Msk[t*512 + (idx>>6)] bit l = spike of idx=(idx&~63)|l.
// ---------------------------------------------------------------------------
__global__ __launch_bounds__(128)
void lif_scan(const float* __restrict__ ff, const float* __restrict__ st0,
              const float* __restrict__ leak_v, const float* __restrict__ thresh,
              float* __restrict__ spikes, float* __restrict__ states,
              unsigned long long* __restrict__ Msk)
{
    const int idx = blockIdx.x * 128 + threadIdx.x;
    const int n = idx & (N_SZ - 1);
    const int b = idx >> 9;

    float v = st0[idx];
    float s = st0[BN_TOT + idx];
    const float lv = leak_v[n];
    const float th = thresh[n];

    const float* fp = ff + (size_t)b * T_STEPS * N_SZ + n;
    float* sp  = spikes + idx;
    float* stp = states + idx;
    const int wslot = idx >> 6;
    const bool wlead = ((threadIdx.x & 63) == 0);

    float f[8];
#pragma unroll
    for (int j = 0; j < 8; ++j) f[j] = fp[(size_t)j * N_SZ];

    for (int t = 0; t < T_STEPS; t += 8) {
        float g[8];
#pragma unroll
        for (int j = 0; j < 8; ++j) g[j] = 0.f;
        if (t + 8 < T_STEPS) {
            const float* q = fp + (size_t)(t + 8) * N_SZ;
#pragma unroll
            for (int j = 0; j < 8; ++j) g[j] = q[(size_t)j * N_SZ];
        }
#pragma unroll
        for (int j = 0; j < 8; ++j) {
            v = lv * v * (1.0f - s) + f[j];
            s = (v > th) ? 1.0f : 0.0f;
            size_t o  = (size_t)(t + j) * BN_TOT;
            size_t o2 = (size_t)(t + j) * (2 * BN_TOT);
            sp[o] = s;
            stp[o2] = v;
            stp[o2 + BN_TOT] = s;
            unsigned long long bm = __ballot(s != 0.0f);
            if (Msk && wlead)
                Msk[(size_t)(t + j) * 512 + wslot] = bm;
        }
#pragma unroll
        for (int j = 0; j < 8; ++j) f[j] = g[j];
    }
}

// ---------------------------------------------------------------------------
// scan2: u[t] = leak_i*u[t-1] + y[t], in place over dec ([t][b][n]);
// 8-deep prefetch.
// ---------------------------------------------------------------------------
__global__ __launch_bounds__(128)
void li_scan(float* __restrict__ dec, const float* __restrict__ u0,
             const float* __restrict__ leak_i)
{
    const int idx = blockIdx.x * 128 + threadIdx.x;
    const int n = idx & (N_SZ - 1);

    float u = u0[idx];
    const float li = leak_i[n];
    float* p = dec + idx;

    float y[8];
#pragma unroll
    for (int j = 0; j < 8; ++j) y[j] = p[(size_t)j * BN_TOT];

    for (int t = 0; t < T_STEPS; t += 8) {
        float g[8];
#pragma unroll
        for (int j = 0; j < 8; ++j) g[j] = 0.f;
        if (t + 8 < T_STEPS) {
            float* q = p + (size_t)(t + 8) * BN_TOT;
#pragma unroll
            for (int j = 0; j < 8; ++j) g[j] = q[(size_t)j * BN_TOT];
        }
#pragma unroll
        for (int j = 0; j < 8; ++j) {
            u = fmaf(li, u, y[j]);
            p[(size_t)(t + j) * BN_TOT] = u;
        }
#pragma unroll
        for (int j = 0; j < 8; ++j) y[j] = g[j];
    }
}

// ---------------------------------------------------------------------------
extern "C" void kernel_launch(void* const* d_in, const int* in_sizes, int n_in,
                              void* d_out, int out_size, void* d_ws, size_t ws_size,
                              hipStream_t stream)
{
    (void)in_sizes; (void)n_in; (void)out_size;

    const float* X     = (const float*)d_in[0];
    const float* st_sn = (const float*)d_in[1];
    const float* st_li = (const float*)d_in[2];
    const float* W1    = (const float*)d_in[3];
    const float* W2    = (const float*)d_in[4];
    const float* lv    = (const float*)d_in[5];
    const float* li    = (const float*)d_in[6];
    const float* th    = (const float*)d_in[7];

    float* spikes = (float*)d_out;                // [T][B][N]
    float* states = spikes + TBN;                 // [T][2][B][N]
    float* dec    = states + 2 * TBN;             // [T][B][N]

    // ws layout: Wc [512][512] bf16 (0.5 MiB) + spike mask [1000][512] u64 (4 MiB)
    const size_t WS_NEED = (size_t)512 * 512 * 2 + (size_t)1000 * 512 * 8;
    const bool use_mfma = (ws_size >= WS_NEED);
    ushort_t* Wc = (ushort_t*)d_ws;
    unsigned long long* Msk = (unsigned long long*)(Wc + (size_t)512 * 512);

    const dim3 gemm_grid(4, 500), gemm_block(256);
    const dim3 scan_grid(BN_TOT / 128), scan_block(128);

    if (use_mfma)
        w2_split<<<dim3(1024), dim3(256), 0, stream>>>(W2, Wc);

    // 1) FF = X @ W1^T (exact fp32 sequential-FMA path) -> dec [b][t][n]
    sgemm_abt<<<gemm_grid, gemm_block, 0, stream>>>(X, W1, dec);

    // 2) (v,s) scan; spikes + states (+ spike bitmask into ws)
    lif_scan<<<scan_grid, scan_block, 0, stream>>>(dec, st_sn, lv, th,
                                                   spikes, states,
                                                   use_mfma ? Msk
                                                            : (unsigned long long*)0);

    // 3) Y = spikes @ W2^T -> dec [t][b][n]
    if (use_mfma)
        gemm2_mfma<<<gemm_grid, gemm_block, 0, stream>>>((const unsigned*)Msk,
                                                         Wc, dec);
    else
        sgemm_abt<<<gemm_grid, gemm_block, 0, stream>>>(spikes, W2, dec);

    // 4) u scan in place over dec
    li_scan<<<scan_grid, scan_block, 0, stream>>>(dec, st_li, li);
}